// Round 3
// baseline (860.717 us; speedup 1.0000x reference)
//
#include <hip/hip_runtime.h>
#include <cstddef>

#define TPB 256
#define KSPLIT 10   // 500 blocks -> ~2 blocks/CU, K-slice = 320

__device__ __forceinline__ float sigmoidf_(float x) {
  return 1.0f / (1.0f + __expf(-x));
}

// jax.image.resize bilinear 21->42, half-pixel centers, edge-renormalized
__device__ __forceinline__ void rzmap(int i, int& j0, int& j1, float& w0, float& w1) {
  if (i == 0)            { j0 = 0;  j1 = 0;  w0 = 1.0f;  w1 = 0.0f; }
  else if (i == 41)      { j0 = 20; j1 = 20; w0 = 1.0f;  w1 = 0.0f; }
  else if ((i & 1) == 0) { int k = i >> 1; j0 = k - 1; j1 = k;     w0 = 0.25f; w1 = 0.75f; }
  else                   { int k = i >> 1; j0 = k;     j1 = k + 1; w0 = 0.75f; w1 = 0.25f; }
}

// K1: per (b, group of 32 ch): gates (means -> dwconv -> GN -> sigmoid) and
// gated projection onto mb1_w accumulated atomically into plc[b][16][441].
__global__ __launch_bounds__(256) void k1_gate_proj(
    const float* __restrict__ FL, const float* __restrict__ scw,
    const float* __restrict__ gng, const float* __restrict__ gnb,
    const float* __restrict__ mb1w, float* __restrict__ plc) {
  const int g = blockIdx.x, b = blockIdx.y;
  const int tid = threadIdx.x;
  __shared__ __align__(16) float slab[32 * 441];
  __shared__ float rm[672], cm[672], ch[672], cw[672];
  __shared__ float red[16];

  const float* base = FL + ((size_t)b * 512 + g * 32) * 441;
  const float4* b4 = (const float4*)base;
  float4* sl4 = (float4*)slab;
  for (int i = tid; i < 3528; i += TPB) sl4[i] = b4[i];
  __syncthreads();

  for (int idx = tid; idx < 672; idx += TPB) {
    int c = idx / 21, l = idx - c * 21;
    const float* rowp = slab + c * 441 + l * 21;
    float sr = 0.0f;
    #pragma unroll
    for (int w = 0; w < 21; ++w) sr += rowp[w];
    rm[idx] = sr * (1.0f / 21.0f);
    const float* colp = slab + c * 441 + l;
    float sc = 0.0f;
    #pragma unroll
    for (int h = 0; h < 21; ++h) sc += colp[h * 21];
    cm[idx] = sc * (1.0f / 21.0f);
  }
  __syncthreads();

  for (int idx = tid; idx < 672; idx += TPB) {
    int c = idx / 21, l = idx - c * 21;
    const float* w7 = scw + (g * 32 + c) * 7;
    float ah = 0.0f, aw = 0.0f;
    #pragma unroll
    for (int t = 0; t < 7; ++t) {
      int ll = l + t - 3;
      if (ll >= 0 && ll < 21) {
        float wt = w7[t];
        ah += rm[c * 21 + ll] * wt;
        aw += cm[c * 21 + ll] * wt;
      }
    }
    ch[idx] = ah; cw[idx] = aw;
  }
  __syncthreads();

  float s1 = 0.0f, s2 = 0.0f, s3 = 0.0f, s4v = 0.0f;
  for (int idx = tid; idx < 672; idx += TPB) {
    float x = ch[idx], y = cw[idx];
    s1 += x; s2 += x * x; s3 += y; s4v += y * y;
  }
  #pragma unroll
  for (int off = 32; off; off >>= 1) {
    s1 += __shfl_down(s1, off); s2 += __shfl_down(s2, off);
    s3 += __shfl_down(s3, off); s4v += __shfl_down(s4v, off);
  }
  if ((tid & 63) == 0) {
    int wv = tid >> 6;
    red[wv * 4 + 0] = s1; red[wv * 4 + 1] = s2;
    red[wv * 4 + 2] = s3; red[wv * 4 + 3] = s4v;
  }
  __syncthreads();
  const float S1 = red[0] + red[4] + red[8] + red[12];
  const float S2 = red[1] + red[5] + red[9] + red[13];
  const float S3 = red[2] + red[6] + red[10] + red[14];
  const float S4 = red[3] + red[7] + red[11] + red[15];
  const float invn = 1.0f / 672.0f;
  const float mh = S1 * invn, vh = S2 * invn - mh * mh;
  const float mw = S3 * invn, vw = S4 * invn - mw * mw;
  const float ivh = rsqrtf(vh + 1e-5f), ivw = rsqrtf(vw + 1e-5f);

  for (int idx = tid; idx < 672; idx += TPB) {
    int c = idx / 21;
    float gamma = gng[g * 32 + c], beta = gnb[g * 32 + c];
    ch[idx] = sigmoidf_((ch[idx] - mh) * ivh * gamma + beta);
    cw[idx] = sigmoidf_((cw[idx] - mw) * ivw * gamma + beta);
  }
  __syncthreads();

  float* pp = plc + (size_t)b * 16 * 441;
  for (int p = tid; p < 441; p += TPB) {
    int i = p / 21, j = p - i * 21;
    float acc[16];
    #pragma unroll
    for (int o = 0; o < 16; ++o) acc[o] = 0.0f;
    #pragma unroll 4
    for (int c = 0; c < 32; ++c) {
      float v = slab[c * 441 + p] * ch[c * 21 + i] * cw[c * 21 + j];
      const float* wc = mb1w + g * 32 + c;  // uniform addresses -> s_load
      #pragma unroll
      for (int o = 0; o < 16; ++o) acc[o] += v * wc[o * 512];
    }
    #pragma unroll
    for (int o = 0; o < 16; ++o) atomicAdd(pp + (size_t)o * 441 + p, acc[o]);
  }
}

// K2: bilinear resize of 16-ch plc -> bn -> relu -> mb2 -> sigmoid mask; sow sums
__global__ __launch_bounds__(256) void k2_mask(
    const float* __restrict__ plc, const float* __restrict__ mb1b,
    const float* __restrict__ bng, const float* __restrict__ bnb,
    const float* __restrict__ mb2w, const float* __restrict__ mb2b,
    float* __restrict__ mask, float* __restrict__ sow) {
  const int b = blockIdx.x;
  const int p = blockIdx.y * TPB + threadIdx.x;
  float macc[5] = {0, 0, 0, 0, 0};
  if (p < 1764) {
    int y = p / 42, x = p - y * 42;
    int jy0, jy1, jx0, jx1; float wy0, wy1, wx0, wx1;
    rzmap(y, jy0, jy1, wy0, wy1);
    rzmap(x, jx0, jx1, wx0, wx1);
    const float RSQ = rsqrtf(1.0f + 1e-5f);
    const float* pb = plc + (size_t)b * 16 * 441;
    float h[16];
    #pragma unroll
    for (int o = 0; o < 16; ++o) {
      const float* po = pb + o * 441;
      float hm = wy0 * (wx0 * po[jy0 * 21 + jx0] + wx1 * po[jy0 * 21 + jx1]) +
                 wy1 * (wx0 * po[jy1 * 21 + jx0] + wx1 * po[jy1 * 21 + jx1]);
      float t = (hm + mb1b[o]) * (bng[o] * RSQ) + bnb[o];
      h[o] = t > 0.0f ? t : 0.0f;
    }
    #pragma unroll
    for (int d = 0; d < 5; ++d) {
      float acc = mb2b[d];
      #pragma unroll
      for (int o = 0; o < 16; ++o) acc += mb2w[d * 16 + o] * h[o];
      float mv = sigmoidf_(acc);
      mask[((size_t)b * 5 + d) * 1764 + p] = mv;
      macc[d] = mv;
    }
  }
  #pragma unroll
  for (int off = 32; off; off >>= 1) {
    #pragma unroll
    for (int d = 0; d < 5; ++d) macc[d] += __shfl_down(macc[d], off);
  }
  if ((threadIdx.x & 63) == 0) {
    #pragma unroll
    for (int d = 0; d < 5; ++d) atomicAdd(&sow[b * 5 + d], macc[d]);
  }
}

// K3pre: vec_pad row 100 = bn1d_b (virtual GEMM row -> per-n constant),
// rows 101..127 = 0
__global__ __launch_bounds__(256) void k3pre(
    const float* __restrict__ b1d, float* __restrict__ vp) {
  int i = blockIdx.x * TPB + threadIdx.x;
  if (i >= 28 * 3200) return;
  int r = i / 3200, k = i - r * 3200;
  vp[(size_t)(100 + r) * 3200 + k] = (r == 0) ? b1d[k] : 0.0f;
}

// K3: vec[b,c,d] = (sum_p F1[b,c,p]*mask[b,d,p]) / (sow+1e-5).
// Each wave processes 4 channels simultaneously -> mask LDS reads amortized 4x.
__global__ __launch_bounds__(256) void k3_vec(
    const float* __restrict__ F1, const float* __restrict__ mask,
    const float* __restrict__ sow, const float* __restrict__ g1d,
    float* __restrict__ vec_pad, float* __restrict__ vec_r) {
  const int ct = blockIdx.x, b = blockIdx.y;
  __shared__ float4 mkv[2205];
  const float4* msrc = (const float4*)(mask + (size_t)b * 8820);
  for (int i = threadIdx.x; i < 2205; i += TPB) mkv[i] = msrc[i];
  __syncthreads();
  const int wv = threadIdx.x >> 6, lane = threadIdx.x & 63;
  const int c0 = ct * 16 + wv * 4;
  const float4* f0 = (const float4*)(F1 + ((size_t)b * 640 + c0) * 1764);
  float a[4][5] = {};
  for (int q = lane; q < 441; q += 64) {
    float4 f[4];
    #pragma unroll
    for (int j = 0; j < 4; ++j) f[j] = f0[(size_t)j * 441 + q];
    #pragma unroll
    for (int d = 0; d < 5; ++d) {
      float4 m = mkv[d * 441 + q];
      #pragma unroll
      for (int j = 0; j < 4; ++j)
        a[j][d] += f[j].x * m.x + f[j].y * m.y + f[j].z * m.z + f[j].w * m.w;
    }
  }
  #pragma unroll
  for (int off = 32; off; off >>= 1) {
    #pragma unroll
    for (int j = 0; j < 4; ++j)
      #pragma unroll
      for (int d = 0; d < 5; ++d)
        a[j][d] += __shfl_down(a[j][d], off);
  }
  if (lane == 0) {
    const float RSQ = rsqrtf(1.0f + 1e-5f);
    #pragma unroll
    for (int j = 0; j < 4; ++j) {
      #pragma unroll
      for (int d = 0; d < 5; ++d) {
        float inv = 1.0f / (sow[b * 5 + d] + 1e-5f);
        float val = a[j][d] * inv;
        int k = (c0 + j) * 5 + d;
        vec_r[(size_t)b * 3200 + k] = val;
        vec_pad[(size_t)b * 3200 + k] = val * (g1d[k] * RSQ);
      }
    }
  }
}

// K4: register-tiled fp32 GEMM: dacc[ks] = A(vec_pad, 128 rows incl. bias row)
// @ W^T slice. Block tile 128m x 64n, thread tile 8x4, BK=32, K-split 10.
// 500 blocks -> ~2 blocks/CU -> 2 waves/SIMD; per kq: 12 ds_read_b128 vs
// 128 v_fma -> FMA-bound.
__global__ __launch_bounds__(256) void k4_gemm(
    const float* __restrict__ A, const float* __restrict__ W,
    float* __restrict__ dacc) {
  const int n0 = blockIdx.x * 64, ks = blockIdx.y;
  const int tid = threadIdx.x, tx = tid & 15, ty = tid >> 4;
  __shared__ float4 As[8 * 128];  // [kq][m-row]
  __shared__ float4 Ws[8 * 64];   // [kq][n-row]
  const int ar = tid >> 1, aq = (tid & 1) * 4;   // A: 128 rows x 4 f4/thread
  const int wr = tid >> 2, wq = (tid & 3) * 2;   // W: 64 rows x 2 f4/thread
  const float4* Ag = (const float4*)A + (size_t)ar * 800 + ks * 80 + aq;
  const float4* Wg = (const float4*)W + (size_t)(n0 + wr) * 800 + ks * 80 + wq;
  float acc[8][4] = {};
  for (int kk = 0; kk < 10; ++kk) {
    __syncthreads();
    #pragma unroll
    for (int i = 0; i < 4; ++i) As[(aq + i) * 128 + ar] = Ag[kk * 8 + i];
    #pragma unroll
    for (int i = 0; i < 2; ++i) Ws[(wq + i) * 64 + wr] = Wg[kk * 8 + i];
    __syncthreads();
    #pragma unroll
    for (int kq = 0; kq < 8; ++kq) {
      float4 av[8], wv4[4];
      #pragma unroll
      for (int r = 0; r < 8; ++r) av[r] = As[kq * 128 + ty + 16 * r];
      #pragma unroll
      for (int s = 0; s < 4; ++s) wv4[s] = Ws[kq * 64 + tx + 16 * s];
      #pragma unroll
      for (int r = 0; r < 8; ++r)
        #pragma unroll
        for (int s = 0; s < 4; ++s)
          acc[r][s] += av[r].x * wv4[s].x + av[r].y * wv4[s].y +
                       av[r].z * wv4[s].z + av[r].w * wv4[s].w;
    }
  }
  float* dp = dacc + (size_t)ks * 128 * 3200;
  #pragma unroll
  for (int r = 0; r < 8; ++r) {
    int m = ty + 16 * r;
    #pragma unroll
    for (int s = 0; s < 4; ++s)
      dp[(size_t)m * 3200 + n0 + tx + 16 * s] = acc[r][s];
  }
}

// K4b: sum K-slices, add c0 (virtual row 100) + lin_b, elu, combine with vec
__global__ __launch_bounds__(256) void k4b_epi(
    const float* __restrict__ dacc, const float* __restrict__ linb,
    const float* __restrict__ vec_r, float* __restrict__ sup,
    float* __restrict__ outq) {
  int i = blockIdx.x * TPB + threadIdx.x;
  if (i >= 320000) return;
  int m = i / 3200, n = i - m * 3200;
  const size_t S = (size_t)128 * 3200;
  size_t o = (size_t)m * 3200 + n;
  size_t oc = (size_t)100 * 3200 + n;
  float d = 0.0f, c0 = 0.0f;
  #pragma unroll
  for (int ks = 0; ks < KSPLIT; ++ks) {
    d  += dacc[ks * S + o];
    c0 += dacc[ks * S + oc];
  }
  float dv = d + c0 + linb[n];
  float z = dv > 0.0f ? dv : expm1f(dv);
  float out = 0.5f * z + 0.5f * vec_r[i];
  if (m < 25) sup[(size_t)m * 3200 + n] = out;
  else outq[(size_t)(m - 20) * 3200 + n] = out;  // query rows 5..79 of d_out
}

// K5: support = mean over 5 shots of first 25 rows
__global__ __launch_bounds__(256) void k5_support(
    const float* __restrict__ sup, float* __restrict__ outp) {
  int idx = blockIdx.x * TPB + threadIdx.x;
  if (idx >= 16000) return;
  int w = idx / 3200, n = idx - w * 3200;
  float s = 0.0f;
  #pragma unroll
  for (int t = 0; t < 5; ++t) s += sup[(size_t)(w * 5 + t) * 3200 + n];
  outp[idx] = s * 0.2f;
}

extern "C" void kernel_launch(void* const* d_in, const int* in_sizes, int n_in,
                              void* d_out, int out_size, void* d_ws, size_t ws_size,
                              hipStream_t stream) {
  const float* F1   = (const float*)d_in[0];
  const float* FL   = (const float*)d_in[1];
  const float* scw  = (const float*)d_in[2];
  const float* gng  = (const float*)d_in[3];
  const float* gnb  = (const float*)d_in[4];
  const float* mb1w = (const float*)d_in[5];
  const float* mb1b = (const float*)d_in[6];
  const float* bng  = (const float*)d_in[7];
  const float* bnb  = (const float*)d_in[8];
  const float* mb2w = (const float*)d_in[9];
  const float* mb2b = (const float*)d_in[10];
  const float* g1d  = (const float*)d_in[11];
  const float* b1d  = (const float*)d_in[12];
  const float* linw = (const float*)d_in[13];
  const float* linb = (const float*)d_in[14];

  float* ws      = (float*)d_ws;
  float* plc     = ws;                 // 705600
  float* sow     = ws + 705600;        // 512
  float* mask    = ws + 706112;        // 882000
  float* vec_pad = ws + 1588112;       // 128*3200 = 409600
  float* vec_r   = ws + 1997712;       // 320000
  float* dacc    = ws + 2317712;       // KSPLIT*128*3200 = 4096000
  float* sup     = ws + 6413712;       // 80000  (total ~26 MB)
  float* out     = (float*)d_out;

  hipMemsetAsync(plc, 0, (size_t)706112 * sizeof(float), stream);  // plc + sow
  k3pre<<<dim3(350), TPB, 0, stream>>>(b1d, vec_pad);
  k1_gate_proj<<<dim3(16, 100), TPB, 0, stream>>>(FL, scw, gng, gnb, mb1w, plc);
  k2_mask<<<dim3(100, 7), TPB, 0, stream>>>(plc, mb1b, bng, bnb, mb2w, mb2b, mask, sow);
  k3_vec<<<dim3(40, 100), TPB, 0, stream>>>(F1, mask, sow, g1d, vec_pad, vec_r);
  k4_gemm<<<dim3(50, KSPLIT), TPB, 0, stream>>>(vec_pad, linw, dacc);
  k4b_epi<<<dim3(1250), TPB, 0, stream>>>(dacc, linb, vec_r, sup, out);
  k5_support<<<dim3(63), TPB, 0, stream>>>(sup, out);
}